// Round 8
// baseline (1281.919 us; speedup 1.0000x reference)
//
#include <hip/hip_runtime.h>
#include <math.h>

#define T_LEN 3000
#define HID 64

typedef _Float16 f16;
typedef f16 h2 __attribute__((ext_vector_type(2)));

__device__ __forceinline__ float sigmoid_f(float v) {
    return __builtin_amdgcn_rcpf(1.0f + __expf(-v));
}
__device__ __forceinline__ float tanh_f(float v) {
    return fmaf(2.0f, __builtin_amdgcn_rcpf(1.0f + __expf(-2.0f * v)), -1.0f);
}

// DPP lane-XOR permutes (full rows, no bound ctrl):
//  ^1: quad_perm[1,0,3,2]=0xB1   ^2: quad_perm[2,3,0,1]=0x4E
//  ^7: row_half_mirror=0x141 (i<->7-i == i^7 in 3 bits)
//  ^8: row_ror:8=0x128 (rot-8 within 16 == i^8)
template <int CTRL>
__device__ __forceinline__ int dppx(int v) {
    return __builtin_amdgcn_update_dpp(v, v, CTRL, 0xF, 0xF, false);
}

// XOR mask accumulated at dword slot d of the butterfly all-gather.
// Append order: bit0->^32 (bpermute), bit1->^16 (swizzle), bit2->^2,
// bit3->^7, bit4->^8.  (^1 lives inside the dword: f16 slot.)
__host__ __device__ __forceinline__ int Mofd(int d) {
    int m = 0;
    if (d & 1)  m ^= 32;
    if (d & 2)  m ^= 16;
    if (d & 4)  m ^= 2;
    if (d & 8)  m ^= 7;
    if (d & 16) m ^= 8;
    return m;
}

// One wave per batch element, zero barriers, zero LDS on the h critical path.
// R6 post-mortem: weights resident (VGPR 132) but still 786 cyc/step -> the
// ds_write(h)->8x ds_read_b128->lgkmcnt round trip was the cost. R7/R8: h is
// all-gathered in-register via an XOR butterfly (DPP for ^1/^2/^7/^8, 3 DS
// ops for ^16/^32 issued early on small arrays). Lane g's dword d holds
// h[g^M(d)] as f16 pair; weights are loaded k-XOR-permuted per lane to match,
// so the loop needs zero fixups. Dots on DPP-lineage dwords start ~10 cyc
// after h, hiding the DS-op latency.
__global__
__attribute__((amdgpu_flat_work_group_size(64, 64), amdgpu_waves_per_eu(1, 1)))
void gru_bfly(
    const float* __restrict__ x,     // (B, T, 1)
    const float* __restrict__ W_ih,  // (192, 1)
    const float* __restrict__ W_hh,  // (192, 64)
    const float* __restrict__ b_ih,  // (192,)
    const float* __restrict__ b_hh,  // (192,)
    const float* __restrict__ W_fc,  // (1, 64)
    const float* __restrict__ b_fc,  // (1,)
    float* __restrict__ out)         // (B,)
{
    const int b = blockIdx.x;
    const int g = threadIdx.x;  // 0..63, hidden unit index
    const long xbase = (long)b * T_LEN;

    __shared__ float x_lds[64];

    // ---- one-time: W_hh rows for unit g, k-order XOR-permuted per lane ----
    // dword d, f16 slot s  <->  k = g ^ M(d) ^ s
    h2 wr[32], wz[32], wn[32];
    {
        const float* Wr = W_hh + (size_t)(g)       * HID;
        const float* Wz = W_hh + (size_t)(64 + g)  * HID;
        const float* Wn = W_hh + (size_t)(128 + g) * HID;
#pragma unroll
        for (int d = 0; d < 32; ++d) {
            const int k0 = g ^ Mofd(d);
            const int k1 = k0 ^ 1;
            h2 t;
            t.x = (f16)Wr[k0]; t.y = (f16)Wr[k1]; wr[d] = t;
            t.x = (f16)Wz[k0]; t.y = (f16)Wz[k1]; wz[d] = t;
            t.x = (f16)Wn[k0]; t.y = (f16)Wn[k1]; wn[d] = t;
        }
    }
#pragma unroll
    for (int i = 0; i < 32; ++i) {
        asm volatile("" : "+v"(wr[i]), "+v"(wz[i]), "+v"(wn[i]));
    }

    const float wihr = W_ih[g],        wihz = W_ih[64 + g],   wihn = W_ih[128 + g];
    const float br   = b_ih[g]      + b_hh[g];
    const float bz   = b_ih[64 + g] + b_hh[64 + g];
    const float bin  = b_ih[128 + g];
    const float bhn  = b_hh[128 + g];

    // x staging (single wave: DS in-order, wave_barrier only at refill)
    x_lds[g] = x[xbase + g];
    float xnxt = (64 + g < T_LEN) ? x[xbase + 64 + g] : 0.0f;
    float h = 0.0f;  // lane g holds h[g] in fp32
    const int paddr = (g ^ 32) << 2;  // bpermute byte-address, loop-invariant
    __builtin_amdgcn_wave_barrier();

    for (int t = 0; t < T_LEN; ++t) {
        const int j = t & 63;

        // ---- in-register XOR-butterfly all-gather of h ----
        const int ia = __float_as_int(h);
        const int ib = dppx<0xB1>(ia);                       // h[g^1]
        union { __fp16 __attribute__((ext_vector_type(2))) p; int i; } pk;
        pk.p = __builtin_amdgcn_cvt_pkrtz(h, __int_as_float(ib));
        int A[32];
        A[0] = pk.i;                                         // (h[g], h[g^1])
        A[1] = __builtin_amdgcn_ds_bpermute(paddr, A[0]);    // ^32
        A[2] = __builtin_amdgcn_ds_swizzle(A[0], 0x401F);    // ^16
        A[3] = __builtin_amdgcn_ds_swizzle(A[1], 0x401F);
#pragma unroll
        for (int i = 0; i < 4; ++i)  A[4 + i]  = dppx<0x4E>(A[i]);   // ^2
#pragma unroll
        for (int i = 0; i < 8; ++i)  A[8 + i]  = dppx<0x141>(A[i]);  // ^7
#pragma unroll
        for (int i = 0; i < 16; ++i) A[16 + i] = dppx<0x128>(A[i]);  // ^8

        // ---- matvec: 96 v_dot2_f32_f16 against permuted weights ----
        float ar0 = 0.f, ar1 = 0.f, az0 = 0.f, az1 = 0.f, an0 = 0.f, an1 = 0.f;
#pragma unroll
        for (int d = 0; d < 32; d += 2) {
            const h2 h0 = *(h2*)&A[d];
            const h2 h1 = *(h2*)&A[d + 1];
            ar0 = __builtin_amdgcn_fdot2(wr[d],     h0, ar0, false);
            az0 = __builtin_amdgcn_fdot2(wz[d],     h0, az0, false);
            an0 = __builtin_amdgcn_fdot2(wn[d],     h0, an0, false);
            ar1 = __builtin_amdgcn_fdot2(wr[d + 1], h1, ar1, false);
            az1 = __builtin_amdgcn_fdot2(wz[d + 1], h1, az1, false);
            an1 = __builtin_amdgcn_fdot2(wn[d + 1], h1, an1, false);
        }
        const float ar = ar0 + ar1;
        const float az = az0 + az1;
        const float an = an0 + an1;

        const float xt = x_lds[j];
        const float r = sigmoid_f(fmaf(xt, wihr, br) + ar);
        const float z = sigmoid_f(fmaf(xt, wihz, bz) + az);
        const float n = tanh_f(fmaf(xt, wihn, bin) + r * (an + bhn));
        h = fmaf(z, h - n, n);  // (1-z)*n + z*h

        if (j == 63) {
            __builtin_amdgcn_wave_barrier();
            x_lds[g] = xnxt;
            const int idx = t + 65 + g;  // chunk after next
            xnxt = (idx < T_LEN) ? x[xbase + idx] : 0.0f;
            __builtin_amdgcn_wave_barrier();
        }
    }

    // ---- epilogue: out[b] = h . W_fc + b_fc (fp32) ----
    float v = h * W_fc[g];
#pragma unroll
    for (int off = 32; off > 0; off >>= 1) v += __shfl_down(v, off);
    if (g == 0) out[b] = v + b_fc[0];
}

extern "C" void kernel_launch(void* const* d_in, const int* in_sizes, int n_in,
                              void* d_out, int out_size, void* d_ws, size_t ws_size,
                              hipStream_t stream) {
    const float* x    = (const float*)d_in[0];
    const float* W_ih = (const float*)d_in[1];
    const float* W_hh = (const float*)d_in[2];
    const float* b_ih = (const float*)d_in[3];
    const float* b_hh = (const float*)d_in[4];
    const float* W_fc = (const float*)d_in[5];
    const float* b_fc = (const float*)d_in[6];
    float* out = (float*)d_out;

    const int B = 256;  // in_sizes[0] = B*T = 768000 -> B=256, T=3000
    gru_bfly<<<B, 64, 0, stream>>>(x, W_ih, W_hh, b_ih, b_hh, W_fc, b_fc, out);
}

// Round 9
// 1054.641 us; speedup vs baseline: 1.2155x; 1.2155x over previous
//
#include <hip/hip_runtime.h>
#include <math.h>

#define T_LEN 3000
#define HID 64

typedef _Float16 f16;
typedef f16 h2 __attribute__((ext_vector_type(2)));

__device__ __forceinline__ float sigmoid_f(float v) {
    return __builtin_amdgcn_rcpf(1.0f + __expf(-v));
}
__device__ __forceinline__ float tanh_f(float v) {
    return fmaf(2.0f, __builtin_amdgcn_rcpf(1.0f + __expf(-2.0f * v)), -1.0f);
}

// R9: 4-wave k-split. R6/R8 showed a single wave is VALU-issue-bound
// (~280 insts/step on one SIMD). Here wave w owns k-slice [16w,16w+16):
// each lane does 24 dot2 (48 cyc) for its 3 gate rows, partials reduced
// through LDS by wave 0 (lane k owns h[k] fp32 across steps), h broadcast
// back as f16 (2x ds_read_b128, same-address = free). 2 s_barriers/step.
// Weight footprint: 24 dwords/lane -> zero register pressure.
__global__ __launch_bounds__(256, 1) void gru_ksplit(
    const float* __restrict__ x,     // (B, T, 1)
    const float* __restrict__ W_ih,  // (192, 1)
    const float* __restrict__ W_hh,  // (192, 64)
    const float* __restrict__ b_ih,  // (192,)
    const float* __restrict__ b_hh,  // (192,)
    const float* __restrict__ W_fc,  // (1, 64)
    const float* __restrict__ b_fc,  // (1,)
    float* __restrict__ out)         // (B,)
{
    const int b    = blockIdx.x;
    const int tid  = threadIdx.x;
    const int wave = tid >> 6;   // 0..3: k-slice [16*wave, 16*wave+16)
    const int l    = tid & 63;   // row index within each gate
    const long xbase = (long)b * T_LEN;

    __shared__ __align__(16) f16 h_lds[HID];   // 128 B, broadcast as 8 x float4
    __shared__ float psum[4][3 * HID];         // [wave][gate*64 + l]
    __shared__ float x_lds[128];               // double-buffered x chunks

    // ---- one-time: W_hh rows l / 64+l / 128+l, k-slice of this wave ----
    h2 wr[8], wz[8], wn[8];
    {
        const float* Wr = W_hh + (size_t)(l)        * HID + wave * 16;
        const float* Wz = W_hh + (size_t)(64 + l)   * HID + wave * 16;
        const float* Wn = W_hh + (size_t)(128 + l)  * HID + wave * 16;
#pragma unroll
        for (int j = 0; j < 8; ++j) {
            h2 t;
            t.x = (f16)Wr[2*j]; t.y = (f16)Wr[2*j+1]; wr[j] = t;
            t.x = (f16)Wz[2*j]; t.y = (f16)Wz[2*j+1]; wz[j] = t;
            t.x = (f16)Wn[2*j]; t.y = (f16)Wn[2*j+1]; wn[j] = t;
        }
    }
#pragma unroll
    for (int j = 0; j < 8; ++j) {
        asm volatile("" : "+v"(wr[j]), "+v"(wz[j]), "+v"(wn[j]));
    }

    // tail constants (used by wave 0 only; harmless elsewhere)
    const float wihr = W_ih[l],        wihz = W_ih[64 + l],   wihn = W_ih[128 + l];
    const float br   = b_ih[l]       + b_hh[l];
    const float bz   = b_ih[64 + l]  + b_hh[64 + l];
    const float bin  = b_ih[128 + l];
    const float bhn  = b_hh[128 + l];

    // init h and the first two x chunks
    if (wave == 0) h_lds[l] = (f16)0.0f;
    if (tid < 128) x_lds[tid] = x[xbase + tid];   // 128 < T_LEN
    float h = 0.0f;  // wave0 lane l holds h[l] in fp32 across steps
    __syncthreads();

    const float4* hb = reinterpret_cast<const float4*>(h_lds);  // 8 x (8 halves)

    for (int t = 0; t < T_LEN; ++t) {
        const int j    = t & 63;
        const int half = (t >> 6) & 1;

        // ---- phase A (all waves): partial dots over this wave's k-slice ----
        union { float4 f; h2 p[4]; } u0, u1;
        u0.f = hb[2 * wave];      // h[16w + 0..7]   (broadcast read)
        u1.f = hb[2 * wave + 1];  // h[16w + 8..15]
        float ar = 0.f, az = 0.f, an = 0.f;
#pragma unroll
        for (int jj = 0; jj < 4; ++jj) {
            ar = __builtin_amdgcn_fdot2(wr[jj],     u0.p[jj], ar, false);
            az = __builtin_amdgcn_fdot2(wz[jj],     u0.p[jj], az, false);
            an = __builtin_amdgcn_fdot2(wn[jj],     u0.p[jj], an, false);
            ar = __builtin_amdgcn_fdot2(wr[4 + jj], u1.p[jj], ar, false);
            az = __builtin_amdgcn_fdot2(wz[4 + jj], u1.p[jj], az, false);
            an = __builtin_amdgcn_fdot2(wn[4 + jj], u1.p[jj], an, false);
        }
        psum[wave][l]        = ar;   // stride-1 across lanes: conflict-free
        psum[wave][64 + l]   = az;
        psum[wave][128 + l]  = an;

        // wave1 stages the next x chunk into the other half (off critical path)
        if (wave == 1 && j == 0) {
            const int tt = t + 64 + l;
            x_lds[(half ^ 1) * 64 + l] = (tt < T_LEN) ? x[xbase + tt] : 0.0f;
        }
        __syncthreads();

        // ---- phase B (wave 0): reduce partials, gate tail, publish h ----
        if (wave == 0) {
            const float sr = (psum[0][l]       + psum[1][l])
                           + (psum[2][l]       + psum[3][l]);
            const float sz = (psum[0][64 + l]  + psum[1][64 + l])
                           + (psum[2][64 + l]  + psum[3][64 + l]);
            const float sn = (psum[0][128 + l] + psum[1][128 + l])
                           + (psum[2][128 + l] + psum[3][128 + l]);
            const float xt = x_lds[half * 64 + j];
            const float r = sigmoid_f(fmaf(xt, wihr, br) + sr);
            const float z = sigmoid_f(fmaf(xt, wihz, bz) + sz);
            const float n = tanh_f(fmaf(xt, wihn, bin) + r * (sn + bhn));
            h = fmaf(z, h - n, n);  // (1-z)*n + z*h, fp32 carried
            h_lds[l] = (f16)h;
        }
        __syncthreads();
    }

    // ---- epilogue: out[b] = h . W_fc + b_fc (wave 0) ----
    if (wave == 0) {
        float v = h * W_fc[l];
#pragma unroll
        for (int off = 32; off > 0; off >>= 1) v += __shfl_down(v, off);
        if (l == 0) out[b] = v + b_fc[0];
    }
}

extern "C" void kernel_launch(void* const* d_in, const int* in_sizes, int n_in,
                              void* d_out, int out_size, void* d_ws, size_t ws_size,
                              hipStream_t stream) {
    const float* x    = (const float*)d_in[0];
    const float* W_ih = (const float*)d_in[1];
    const float* W_hh = (const float*)d_in[2];
    const float* b_ih = (const float*)d_in[3];
    const float* b_hh = (const float*)d_in[4];
    const float* W_fc = (const float*)d_in[5];
    const float* b_fc = (const float*)d_in[6];
    float* out = (float*)d_out;

    const int B = 256;  // in_sizes[0] = B*T = 768000 -> B=256, T=3000
    gru_ksplit<<<B, 256, 0, stream>>>(x, W_ih, W_hh, b_ih, b_hh, W_fc, b_fc, out);
}